// Round 6
// baseline (6518.235 us; speedup 1.0000x reference)
//
#include <hip/hip_runtime.h>
#include <hip/hip_bf16.h>

#define BB 16
#define LL 512
#define DD 512
#define NSEG 3
#define NH 8
#define DH 64
#define AH 256

// ---------------- batched GEMM: C = act(A @ W + bias) ----------------
// A: (z batches) M x K row-major (lda=K), W: K x Nc row-major, C: M x Nc (ldc=Nc)
// grid: (Nc/64, M/64, nbatch); block 256.
__global__ __launch_bounds__(256) void gemm_bias_act(
    const float* __restrict__ A, const float* __restrict__ W,
    const float* __restrict__ bias, float* __restrict__ C,
    int Nc, int K, long bsA, long bsC, int act)
{
  __shared__ float As[32][68];   // As[k][m] (transposed)
  __shared__ float Ws[32][68];   // Ws[k][n]
  const int bx = blockIdx.x, by = blockIdx.y;
  const float* Ab = A + (long)blockIdx.z * bsA + (long)by * 64 * K;
  const float* Wb = W + bx * 64;
  float* Cb = C + (long)blockIdx.z * bsC + (long)by * 64 * Nc + bx * 64;
  const int tid = threadIdx.x;
  const int tx = tid & 15, ty = tid >> 4;
  float acc[4][4] = {};
  for (int k0 = 0; k0 < K; k0 += 32) {
#pragma unroll
    for (int i = 0; i < 2; ++i) {
      int idx = tid + i * 256;
      int r = idx >> 3, kc = (idx & 7) << 2;
      float4 av = *(const float4*)(Ab + (long)r * K + k0 + kc);
      As[kc][r] = av.x; As[kc + 1][r] = av.y; As[kc + 2][r] = av.z; As[kc + 3][r] = av.w;
      int kk = idx >> 4, nc = (idx & 15) << 2;
      float4 wv = *(const float4*)(Wb + (long)(k0 + kk) * Nc + nc);
      *(float4*)&Ws[kk][nc] = wv;
    }
    __syncthreads();
#pragma unroll
    for (int kk = 0; kk < 32; ++kk) {
      float4 a4 = *(const float4*)&As[kk][ty << 2];
      float4 b4 = *(const float4*)&Ws[kk][tx << 2];
      float av[4] = {a4.x, a4.y, a4.z, a4.w};
      float bv[4] = {b4.x, b4.y, b4.z, b4.w};
#pragma unroll
      for (int i = 0; i < 4; ++i)
#pragma unroll
        for (int j = 0; j < 4; ++j) acc[i][j] = fmaf(av[i], bv[j], acc[i][j]);
    }
    __syncthreads();
  }
  float4 bv4 = *(const float4*)(bias + bx * 64 + (tx << 2));
  float bb[4] = {bv4.x, bv4.y, bv4.z, bv4.w};
#pragma unroll
  for (int i = 0; i < 4; ++i) {
    float4 o;
    float* op = &o.x;
#pragma unroll
    for (int j = 0; j < 4; ++j) {
      float v = acc[i][j] + bb[j];
      if (act) v = fmaxf(v, 0.f);
      op[j] = v;
    }
    *(float4*)(Cb + (long)((ty << 2) + i) * Nc + (tx << 2)) = o;
  }
}

// ---------------- h2 = relu(se @ w2[n] + b2[n]) ----------------
__global__ __launch_bounds__(256) void h2_kernel(
    const float* __restrict__ se, const float* __restrict__ w2,
    const float* __restrict__ b2, float* __restrict__ h2)
{
  __shared__ float ses[DD];
  const int bn = blockIdx.x;          // b*NSEG + n
  const int n = bn % NSEG;
  const int t = threadIdx.x;
  ses[t] = se[(long)bn * DD + t];
  ses[t + 256] = se[(long)bn * DD + t + 256];
  __syncthreads();
  const float* wn = w2 + (long)n * DD * DD;
  for (int j = t; j < DD; j += 256) {
    float acc = b2[n * DD + j];
    for (int k = 0; k < DD; ++k) acc = fmaf(ses[k], wn[(long)k * DD + j], acc);
    h2[(long)bn * DD + j] = fmaxf(acc, 0.f);
  }
}

// ---------------- h1 *= h2 (broadcast over l) ----------------
__global__ __launch_bounds__(256) void mult_kernel(float* __restrict__ h1,
                                                   const float* __restrict__ h2)
{
  long i4 = (long)blockIdx.x * 256 + threadIdx.x;   // float4 index; total 3145728
  float4 v = ((float4*)h1)[i4];
  long bn = i4 >> 16;       // / (L*D/4)
  int d4 = (int)(i4 & 127); // % (D/4)
  float4 m = ((const float4*)h2)[bn * 128 + d4];
  v.x *= m.x; v.y *= m.y; v.z *= m.z; v.w *= m.w;
  ((float4*)h1)[i4] = v;
}

// ---------------- local banded attention, in-place residual ----------------
// block: 512 threads = 8 waves (one per head); grid (L, B)
__global__ __launch_bounds__(512) void local_attn(
    float* __restrict__ x, const float* __restrict__ mk,
    const float* __restrict__ ct, const float* __restrict__ mask, long bsX)
{
  const int l = blockIdx.x, b = blockIdx.y;
  const int t = threadIdx.x;
  const int h = t >> 6, d = t & 63;
  const float mkv = mk[((long)b * LL + l) * DD + h * DH + d];
  const float* ctb = ct + (long)b * LL * (2 * DD);
  const float* mb = mask + (long)b * LL;
  float sc[15];
#pragma unroll
  for (int i = 0; i < 15; ++i) {
    int m = l - 7 + i;
    bool valid = (m >= 0) && (m < LL);
    int mc = valid ? m : 0;
    float p = mkv * ctb[(long)mc * (2 * DD) + h * DH + d];
#pragma unroll
    for (int o = 32; o > 0; o >>= 1) p += __shfl_xor(p, o, 64);
    float s = p * 0.125f;
    if (mb[mc] == 0.f) s = -1e9f;
    sc[i] = valid ? s : -3e9f;
  }
  float mx = sc[0];
#pragma unroll
  for (int i = 1; i < 15; ++i) mx = fmaxf(mx, sc[i]);
  float sum = 0.f;
#pragma unroll
  for (int i = 0; i < 15; ++i) { sc[i] = __expf(sc[i] - mx); sum += sc[i]; }
  const float inv = 1.f / sum;
  float r = 0.f;
#pragma unroll
  for (int i = 0; i < 15; ++i) {
    int m = l - 7 + i;
    int mc = (m < 0) ? 0 : ((m >= LL) ? (LL - 1) : m);
    r = fmaf(sc[i], ctb[(long)mc * (2 * DD) + DD + h * DH + d], r);
  }
  x[(long)b * bsX + (long)l * DD + h * DH + d] += r * inv;
}

// ---------------- global attention (flash-style), in-place residual ----------------
__global__ __launch_bounds__(512) void global_attn(
    float* __restrict__ x, const float* __restrict__ mk,
    const float* __restrict__ ct, const float* __restrict__ mask)
{
  const int l = blockIdx.x, b = blockIdx.y;
  const int h = threadIdx.x >> 6, d = threadIdx.x & 63;
  const float mkv = mk[((long)b * LL + l) * DD + h * DH + d];
  const float* ctb = ct + (long)b * LL * (2 * DD) + h * DH + d;
  const float* mb = mask + (long)b * LL;
  float rmax = -1e30f, rsum = 0.f, acc = 0.f;
  for (int m = 0; m < LL; ++m) {
    float p = mkv * ctb[(long)m * (2 * DD)];
#pragma unroll
    for (int o = 32; o > 0; o >>= 1) p += __shfl_xor(p, o, 64);
    float s = p * 0.125f;
    if (mb[m] == 0.f) s = -1e9f;
    float nmax = fmaxf(rmax, s);
    float cor = __expf(rmax - nmax);
    float e = __expf(s - nmax);
    rsum = fmaf(rsum, cor, e);
    acc = acc * cor + e * ctb[(long)m * (2 * DD) + DD];
    rmax = nmax;
  }
  x[((long)b * LL + l) * DD + h * DH + d] += acc / rsum;
}

// ---------------- alpha = tanh(se @ sw1) @ sw2 ----------------
__global__ __launch_bounds__(256) void alpha_kernel(
    const float* __restrict__ se, const float* __restrict__ w1,
    const float* __restrict__ w2, float* __restrict__ alpha)
{
  __shared__ float ses[DD];
  __shared__ float red[4];
  const int bn = blockIdx.x;
  const int t = threadIdx.x;
  ses[t] = se[(long)bn * DD + t];
  ses[t + 256] = se[(long)bn * DD + t + 256];
  __syncthreads();
  float acc = 0.f;
  for (int k = 0; k < DD; ++k) acc = fmaf(ses[k], w1[(long)k * AH + t], acc);
  float v = tanhf(acc) * w2[t];
#pragma unroll
  for (int o = 32; o > 0; o >>= 1) v += __shfl_xor(v, o, 64);
  if ((t & 63) == 0) red[t >> 6] = v;
  __syncthreads();
  if (t == 0) alpha[bn] = red[0] + red[1] + red[2] + red[3];
}

// ---- a[b][l][:] = sum_n sattw[b,n]*ss[b,n,l,:]  (written to f32 out); emit sattw f32 ----
__global__ __launch_bounds__(128) void mix_kernel(
    const float* __restrict__ xbuf, const float* __restrict__ alpha,
    float* __restrict__ abuf, float* __restrict__ outw)
{
  const int l = blockIdx.x, b = blockIdx.y;
  const float a0 = alpha[b * 3 + 0], a1 = alpha[b * 3 + 1], a2 = alpha[b * 3 + 2];
  const float mx = fmaxf(a0, fmaxf(a1, a2));
  const float e0 = __expf(a0 - mx), e1 = __expf(a1 - mx), e2 = __expf(a2 - mx);
  const float inv = 1.f / (e0 + e1 + e2);
  const float w0 = e0 * inv, w1 = e1 * inv, w2 = e2 * inv;
  const float4* x0 = (const float4*)(xbuf + (((long)b * 3 + 0) * LL + l) * DD);
  const float4* x1 = (const float4*)(xbuf + (((long)b * 3 + 1) * LL + l) * DD);
  const float4* x2 = (const float4*)(xbuf + (((long)b * 3 + 2) * LL + l) * DD);
  float4* ar = (float4*)(abuf + ((long)b * LL + l) * DD);
  const int t = threadIdx.x;
  float4 v0 = x0[t], v1 = x1[t], v2 = x2[t];
  float4 o;
  o.x = w0 * v0.x + w1 * v1.x + w2 * v2.x;
  o.y = w0 * v0.y + w1 * v1.y + w2 * v2.y;
  o.z = w0 * v0.z + w1 * v1.z + w2 * v2.z;
  o.w = w0 * v0.w + w1 * v1.w + w2 * v2.w;
  ar[t] = o;
  if (l == 0 && t < 3) {
    float wv = (t == 0) ? w0 : ((t == 1) ? w1 : w2);
    outw[b * 3 + t] = wv;
  }
}

extern "C" void kernel_launch(void* const* d_in, const int* in_sizes, int n_in,
                              void* d_out, int out_size, void* d_ws, size_t ws_size,
                              hipStream_t stream) {
  const float* seg = (const float*)d_in[0];
  const float* msk = (const float*)d_in[1];
  const float* se  = (const float*)d_in[2];
  const float* w1  = (const float*)d_in[3];
  const float* b1  = (const float*)d_in[4];
  const float* w2  = (const float*)d_in[5];
  const float* b2  = (const float*)d_in[6];
  const float* w3  = (const float*)d_in[7];
  const float* b3  = (const float*)d_in[8];
  const float* lcW = (const float*)d_in[9];
  const float* lcb = (const float*)d_in[10];
  const float* lvW = (const float*)d_in[11];
  const float* lvb = (const float*)d_in[12];
  const float* gcW = (const float*)d_in[13];
  const float* gcb = (const float*)d_in[14];
  const float* gvW = (const float*)d_in[15];
  const float* gvb = (const float*)d_in[16];
  const float* sw1 = (const float*)d_in[17];
  const float* sw2 = (const float*)d_in[18];
  float* out = (float*)d_out;                    // f32 output: [a (16*512*512) | sattw (48)]

  const long LD = (long)LL * DD;                 // 262144
  float* ws = (float*)d_ws;
  float* xbuf = ws;                              // B*N*L*D = 12582912
  float* scratch = xbuf + (long)BB * NSEG * LD;  // 12582912 (h1; later mk|ct)
  float* mkbuf = scratch;                        // B*L*D
  float* ctbuf = scratch + (long)BB * LD;        // B*L*2D
  float* h2buf = scratch + (long)BB * NSEG * LD; // B*N*D
  float* alphabuf = h2buf + (long)BB * NSEG * DD;// B*N
  float* abuf = out;                             // final a computed in-place in d_out

  dim3 g88(8, 8, BB), g168(16, 8, BB), blk(256);

  // hyper path
  h2_kernel<<<BB * NSEG, 256, 0, stream>>>(se, w2, b2, h2buf);
  for (int n = 0; n < NSEG; ++n)
    gemm_bias_act<<<g88, blk, 0, stream>>>(seg, w1 + (long)n * DD * DD, b1 + n * DD,
                                           scratch + n * LD, DD, DD, LD, NSEG * LD, 1);
  mult_kernel<<<12288, 256, 0, stream>>>(scratch, h2buf);
  for (int n = 0; n < NSEG; ++n)
    gemm_bias_act<<<g88, blk, 0, stream>>>(scratch + n * LD, w3 + (long)n * DD * DD, b3 + n * DD,
                                           xbuf + n * LD, DD, DD, NSEG * LD, NSEG * LD, 1);

  // local NL blocks (per n, 2 steps each)
  for (int n = 0; n < NSEG; ++n)
    for (int s = 0; s < 2; ++s) {
      const float* vWp = lvW + (long)(n * 2 + s) * DD * DD;
      const float* vbp = lvb + (long)(n * 2 + s) * DD;
      const float* cWp = lcW + (long)(n * 2 + s) * DD * 2 * DD;
      const float* cbp = lcb + (long)(n * 2 + s) * 2 * DD;
      gemm_bias_act<<<g88, blk, 0, stream>>>(xbuf + n * LD, vWp, vbp, mkbuf,
                                             DD, DD, NSEG * LD, LD, 0);
      gemm_bias_act<<<g168, blk, 0, stream>>>(xbuf + n * LD, cWp, cbp, ctbuf,
                                              2 * DD, DD, NSEG * LD, 2 * LD, 0);
      local_attn<<<dim3(LL, BB), 512, 0, stream>>>(xbuf + n * LD, mkbuf, ctbuf, msk,
                                                   (long)NSEG * LD);
    }

  // segment attention mix -> writes a into d_out, sattw into d_out+4194304
  alpha_kernel<<<BB * NSEG, 256, 0, stream>>>(se, sw1, sw2, alphabuf);
  mix_kernel<<<dim3(LL, BB), 128, 0, stream>>>(xbuf, alphabuf, abuf, out + 4194304);

  // global NL blocks, in-place on d_out
  for (int s = 0; s < 2; ++s) {
    gemm_bias_act<<<g88, blk, 0, stream>>>(abuf, gvW + (long)s * DD * DD, gvb + s * DD,
                                           mkbuf, DD, DD, LD, LD, 0);
    gemm_bias_act<<<g168, blk, 0, stream>>>(abuf, gcW + (long)s * DD * 2 * DD,
                                            gcb + s * 2 * DD, ctbuf,
                                            2 * DD, DD, LD, 2 * LD, 0);
    global_attn<<<dim3(LL, BB), 512, 0, stream>>>(abuf, mkbuf, ctbuf, msk);
  }
}

// Round 8
// 2820.657 us; speedup vs baseline: 2.3109x; 2.3109x over previous
//
#include <hip/hip_runtime.h>
#include <hip/hip_bf16.h>

#define BB 16
#define LL 512
#define DD 512
#define NSEG 3
#define NH 8
#define DH 64
#define AH 256

// ---------------- batched GEMM: C = act(A @ W + bias) ----------------
// A: (z batches) M x K row-major (lda=K), W: K x Nc row-major, C: M x Nc (ldc=Nc)
// grid: (Nc/64, M/64, nbatch); block 256.
__global__ __launch_bounds__(256) void gemm_bias_act(
    const float* __restrict__ A, const float* __restrict__ W,
    const float* __restrict__ bias, float* __restrict__ C,
    int Nc, int K, long bsA, long bsC, int act)
{
  __shared__ float As[32][68];   // As[k][m] (transposed)
  __shared__ float Ws[32][68];   // Ws[k][n]
  const int bx = blockIdx.x, by = blockIdx.y;
  const float* Ab = A + (long)blockIdx.z * bsA + (long)by * 64 * K;
  const float* Wb = W + bx * 64;
  float* Cb = C + (long)blockIdx.z * bsC + (long)by * 64 * Nc + bx * 64;
  const int tid = threadIdx.x;
  const int tx = tid & 15, ty = tid >> 4;
  float acc[4][4] = {};
  for (int k0 = 0; k0 < K; k0 += 32) {
#pragma unroll
    for (int i = 0; i < 2; ++i) {
      int idx = tid + i * 256;
      int r = idx >> 3, kc = (idx & 7) << 2;
      float4 av = *(const float4*)(Ab + (long)r * K + k0 + kc);
      As[kc][r] = av.x; As[kc + 1][r] = av.y; As[kc + 2][r] = av.z; As[kc + 3][r] = av.w;
      int kk = idx >> 4, nc = (idx & 15) << 2;
      float4 wv = *(const float4*)(Wb + (long)(k0 + kk) * Nc + nc);
      *(float4*)&Ws[kk][nc] = wv;
    }
    __syncthreads();
#pragma unroll
    for (int kk = 0; kk < 32; ++kk) {
      float4 a4 = *(const float4*)&As[kk][ty << 2];
      float4 b4 = *(const float4*)&Ws[kk][tx << 2];
      float av[4] = {a4.x, a4.y, a4.z, a4.w};
      float bv[4] = {b4.x, b4.y, b4.z, b4.w};
#pragma unroll
      for (int i = 0; i < 4; ++i)
#pragma unroll
        for (int j = 0; j < 4; ++j) acc[i][j] = fmaf(av[i], bv[j], acc[i][j]);
    }
    __syncthreads();
  }
  float4 bv4 = *(const float4*)(bias + bx * 64 + (tx << 2));
  float bb[4] = {bv4.x, bv4.y, bv4.z, bv4.w};
#pragma unroll
  for (int i = 0; i < 4; ++i) {
    float4 o;
    float* op = &o.x;
#pragma unroll
    for (int j = 0; j < 4; ++j) {
      float v = acc[i][j] + bb[j];
      if (act) v = fmaxf(v, 0.f);
      op[j] = v;
    }
    *(float4*)(Cb + (long)((ty << 2) + i) * Nc + (tx << 2)) = o;
  }
}

// ---------------- h2 = relu(se @ w2[n] + b2[n]) ----------------
__global__ __launch_bounds__(256) void h2_kernel(
    const float* __restrict__ se, const float* __restrict__ w2,
    const float* __restrict__ b2, float* __restrict__ h2)
{
  __shared__ float ses[DD];
  const int bn = blockIdx.x;          // b*NSEG + n
  const int n = bn % NSEG;
  const int t = threadIdx.x;
  ses[t] = se[(long)bn * DD + t];
  ses[t + 256] = se[(long)bn * DD + t + 256];
  __syncthreads();
  const float* wn = w2 + (long)n * DD * DD;
  for (int j = t; j < DD; j += 256) {
    float acc = b2[n * DD + j];
    for (int k = 0; k < DD; ++k) acc = fmaf(ses[k], wn[(long)k * DD + j], acc);
    h2[(long)bn * DD + j] = fmaxf(acc, 0.f);
  }
}

// ---------------- h1 *= h2 (broadcast over l) ----------------
__global__ __launch_bounds__(256) void mult_kernel(float* __restrict__ h1,
                                                   const float* __restrict__ h2)
{
  long i4 = (long)blockIdx.x * 256 + threadIdx.x;   // float4 index; total 3145728
  float4 v = ((float4*)h1)[i4];
  long bn = i4 >> 16;       // / (L*D/4)
  int d4 = (int)(i4 & 127); // % (D/4)
  float4 m = ((const float4*)h2)[bn * 128 + d4];
  v.x *= m.x; v.y *= m.y; v.z *= m.z; v.w *= m.w;
  ((float4*)h1)[i4] = v;
}

// ---------------- local banded attention, in-place residual ----------------
__global__ __launch_bounds__(512) void local_attn(
    float* __restrict__ x, const float* __restrict__ mk,
    const float* __restrict__ ct, const float* __restrict__ mask, long bsX)
{
  const int l = blockIdx.x, b = blockIdx.y;
  const int t = threadIdx.x;
  const int h = t >> 6, d = t & 63;
  const float mkv = mk[((long)b * LL + l) * DD + h * DH + d];
  const float* ctb = ct + (long)b * LL * (2 * DD);
  const float* mb = mask + (long)b * LL;
  float sc[15];
#pragma unroll
  for (int i = 0; i < 15; ++i) {
    int m = l - 7 + i;
    bool valid = (m >= 0) && (m < LL);
    int mc = valid ? m : 0;
    float p = mkv * ctb[(long)mc * (2 * DD) + h * DH + d];
#pragma unroll
    for (int o = 32; o > 0; o >>= 1) p += __shfl_xor(p, o, 64);
    float s = p * 0.125f;
    if (mb[mc] == 0.f) s = -1e9f;
    sc[i] = valid ? s : -3e9f;
  }
  float mx = sc[0];
#pragma unroll
  for (int i = 1; i < 15; ++i) mx = fmaxf(mx, sc[i]);
  float sum = 0.f;
#pragma unroll
  for (int i = 0; i < 15; ++i) { sc[i] = __expf(sc[i] - mx); sum += sc[i]; }
  const float inv = 1.f / sum;
  float r = 0.f;
#pragma unroll
  for (int i = 0; i < 15; ++i) {
    int m = l - 7 + i;
    int mc = (m < 0) ? 0 : ((m >= LL) ? (LL - 1) : m);
    r = fmaf(sc[i], ctb[(long)mc * (2 * DD) + DD + h * DH + d], r);
  }
  x[(long)b * bsX + (long)l * DD + h * DH + d] += r * inv;
}

// ---------------- global attention: phase 1, scores ----------------
// S[bh][l][m] = mk[bl,l,h,:]·mq[bl,m,h,:] / 8  (masked); grid (8 mtile, 8 ltile, 64 bh)
__global__ __launch_bounds__(256) void score_kernel(
    const float* __restrict__ mk, const float* __restrict__ ct,
    const float* __restrict__ msk, float* __restrict__ S, int b0)
{
  __shared__ float As[64][65];   // mk^T: As[d][l]
  __shared__ float Bs[64][65];   // mq^T: Bs[d][m]
  const int bz = blockIdx.z;     // chunk-local b*8 + h
  const int bl = bz >> 3, h = bz & 7;
  const int t = threadIdx.x;
  const float* Ab = mk + ((long)bl * LL + blockIdx.y * 64) * DD + h * DH;
  const float* Bb = ct + ((long)bl * LL + blockIdx.x * 64) * (2 * DD) + h * DH;
  {
    int r = t >> 2, c0 = (t & 3) << 4;
#pragma unroll
    for (int i = 0; i < 4; ++i) {
      int c = c0 + i * 4;
      float4 a = *(const float4*)(Ab + (long)r * DD + c);
      As[c][r] = a.x; As[c + 1][r] = a.y; As[c + 2][r] = a.z; As[c + 3][r] = a.w;
      float4 q = *(const float4*)(Bb + (long)r * (2 * DD) + c);
      Bs[c][r] = q.x; Bs[c + 1][r] = q.y; Bs[c + 2][r] = q.z; Bs[c + 3][r] = q.w;
    }
  }
  __syncthreads();
  const int tx = t & 15, ty = t >> 4;
  float acc[4][4] = {};
#pragma unroll 8
  for (int d = 0; d < 64; ++d) {
    float a4[4], b4[4];
#pragma unroll
    for (int i = 0; i < 4; ++i) { a4[i] = As[d][(ty << 2) + i]; b4[i] = Bs[d][(tx << 2) + i]; }
#pragma unroll
    for (int i = 0; i < 4; ++i)
#pragma unroll
      for (int j = 0; j < 4; ++j) acc[i][j] = fmaf(a4[i], b4[j], acc[i][j]);
  }
  const float* mrow = msk + (long)(b0 + bl) * LL + blockIdx.x * 64 + (tx << 2);
  float mv[4];
#pragma unroll
  for (int j = 0; j < 4; ++j) mv[j] = mrow[j];
  float* Sb = S + ((long)bz * LL + blockIdx.y * 64) * LL + blockIdx.x * 64;
#pragma unroll
  for (int i = 0; i < 4; ++i) {
    float4 o;
    float* op = &o.x;
#pragma unroll
    for (int j = 0; j < 4; ++j)
      op[j] = (mv[j] == 0.f) ? -1e9f : acc[i][j] * 0.125f;
    *(float4*)(Sb + (long)((ty << 2) + i) * LL + (tx << 2)) = o;
  }
}

// ---------------- global attention: phase 2, row softmax (wave per row) ----------------
__global__ __launch_bounds__(256) void smax_kernel(float* __restrict__ S)
{
  const int w = threadIdx.x >> 6, lane = threadIdx.x & 63;
  long row = (long)blockIdx.x * 4 + w;
  float* p = S + row * LL;
  float v[8];
  float mx = -3e38f;
#pragma unroll
  for (int i = 0; i < 8; ++i) { v[i] = p[lane + i * 64]; mx = fmaxf(mx, v[i]); }
#pragma unroll
  for (int o = 32; o > 0; o >>= 1) mx = fmaxf(mx, __shfl_xor(mx, o, 64));
  float sum = 0.f;
#pragma unroll
  for (int i = 0; i < 8; ++i) { v[i] = __expf(v[i] - mx); sum += v[i]; }
#pragma unroll
  for (int o = 32; o > 0; o >>= 1) sum += __shfl_xor(sum, o, 64);
  const float inv = 1.f / sum;
#pragma unroll
  for (int i = 0; i < 8; ++i) p[lane + i * 64] = v[i] * inv;
}

// ---------------- global attention: phase 3, PV + residual ----------------
// out[b0+bl, l, h*64+d] += sum_m S[bh][l][m] * mv[bl, m, h*64+d]; grid (8 ltile, 64 bh)
__global__ __launch_bounds__(256) void pv_kernel(
    const float* __restrict__ S, const float* __restrict__ ct,
    float* __restrict__ out, int b0)
{
  __shared__ float As[32][68];   // S^T tile: As[k][l]
  __shared__ float Bs[32][68];   // V tile:  Bs[k][d]
  const int bz = blockIdx.y;     // chunk-local b*8 + h
  const int bl = bz >> 3, h = bz & 7;
  const float* Ab = S + ((long)bz * LL + blockIdx.x * 64) * LL;
  const float* Bb = ct + (long)bl * LL * (2 * DD) + DD + h * DH;
  float* Cb = out + ((long)(b0 + bl) * LL + blockIdx.x * 64) * DD + h * DH;
  const int tid = threadIdx.x;
  const int tx = tid & 15, ty = tid >> 4;
  float acc[4][4] = {};
  for (int k0 = 0; k0 < LL; k0 += 32) {
#pragma unroll
    for (int i = 0; i < 2; ++i) {
      int idx = tid + i * 256;
      int r = idx >> 3, kc = (idx & 7) << 2;
      float4 av = *(const float4*)(Ab + (long)r * LL + k0 + kc);
      As[kc][r] = av.x; As[kc + 1][r] = av.y; As[kc + 2][r] = av.z; As[kc + 3][r] = av.w;
      int kk = idx >> 4, nc = (idx & 15) << 2;
      float4 bv = *(const float4*)(Bb + (long)(k0 + kk) * (2 * DD) + nc);
      *(float4*)&Bs[kk][nc] = bv;
    }
    __syncthreads();
#pragma unroll
    for (int kk = 0; kk < 32; ++kk) {
      float4 a4 = *(const float4*)&As[kk][ty << 2];
      float4 b4 = *(const float4*)&Bs[kk][tx << 2];
      float av[4] = {a4.x, a4.y, a4.z, a4.w};
      float bv[4] = {b4.x, b4.y, b4.z, b4.w};
#pragma unroll
      for (int i = 0; i < 4; ++i)
#pragma unroll
        for (int j = 0; j < 4; ++j) acc[i][j] = fmaf(av[i], bv[j], acc[i][j]);
    }
    __syncthreads();
  }
#pragma unroll
  for (int i = 0; i < 4; ++i) {
    float* cp = Cb + (long)((ty << 2) + i) * DD + (tx << 2);
    float4 o = *(const float4*)cp;
    o.x += acc[i][0]; o.y += acc[i][1]; o.z += acc[i][2]; o.w += acc[i][3];
    *(float4*)cp = o;
  }
}

// ---------------- alpha = tanh(se @ sw1) @ sw2 ----------------
__global__ __launch_bounds__(256) void alpha_kernel(
    const float* __restrict__ se, const float* __restrict__ w1,
    const float* __restrict__ w2, float* __restrict__ alpha)
{
  __shared__ float ses[DD];
  __shared__ float red[4];
  const int bn = blockIdx.x;
  const int t = threadIdx.x;
  ses[t] = se[(long)bn * DD + t];
  ses[t + 256] = se[(long)bn * DD + t + 256];
  __syncthreads();
  float acc = 0.f;
  for (int k = 0; k < DD; ++k) acc = fmaf(ses[k], w1[(long)k * AH + t], acc);
  float v = tanhf(acc) * w2[t];
#pragma unroll
  for (int o = 32; o > 0; o >>= 1) v += __shfl_xor(v, o, 64);
  if ((t & 63) == 0) red[t >> 6] = v;
  __syncthreads();
  if (t == 0) alpha[bn] = red[0] + red[1] + red[2] + red[3];
}

// ---- a[b][l][:] = sum_n sattw[b,n]*ss[b,n,l,:] -> f32 out; emit sattw f32 ----
__global__ __launch_bounds__(128) void mix_kernel(
    const float* __restrict__ xbuf, const float* __restrict__ alpha,
    float* __restrict__ abuf, float* __restrict__ outw)
{
  const int l = blockIdx.x, b = blockIdx.y;
  const float a0 = alpha[b * 3 + 0], a1 = alpha[b * 3 + 1], a2 = alpha[b * 3 + 2];
  const float mx = fmaxf(a0, fmaxf(a1, a2));
  const float e0 = __expf(a0 - mx), e1 = __expf(a1 - mx), e2 = __expf(a2 - mx);
  const float inv = 1.f / (e0 + e1 + e2);
  const float w0 = e0 * inv, w1 = e1 * inv, w2 = e2 * inv;
  const float4* x0 = (const float4*)(xbuf + (((long)b * 3 + 0) * LL + l) * DD);
  const float4* x1 = (const float4*)(xbuf + (((long)b * 3 + 1) * LL + l) * DD);
  const float4* x2 = (const float4*)(xbuf + (((long)b * 3 + 2) * LL + l) * DD);
  float4* ar = (float4*)(abuf + ((long)b * LL + l) * DD);
  const int t = threadIdx.x;
  float4 v0 = x0[t], v1 = x1[t], v2 = x2[t];
  float4 o;
  o.x = w0 * v0.x + w1 * v1.x + w2 * v2.x;
  o.y = w0 * v0.y + w1 * v1.y + w2 * v2.y;
  o.z = w0 * v0.z + w1 * v1.z + w2 * v2.z;
  o.w = w0 * v0.w + w1 * v1.w + w2 * v2.w;
  ar[t] = o;
  if (l == 0 && t < 3) {
    float wv = (t == 0) ? w0 : ((t == 1) ? w1 : w2);
    outw[b * 3 + t] = wv;
  }
}

extern "C" void kernel_launch(void* const* d_in, const int* in_sizes, int n_in,
                              void* d_out, int out_size, void* d_ws, size_t ws_size,
                              hipStream_t stream) {
  const float* seg = (const float*)d_in[0];
  const float* msk = (const float*)d_in[1];
  const float* se  = (const float*)d_in[2];
  const float* w1  = (const float*)d_in[3];
  const float* b1  = (const float*)d_in[4];
  const float* w2  = (const float*)d_in[5];
  const float* b2  = (const float*)d_in[6];
  const float* w3  = (const float*)d_in[7];
  const float* b3  = (const float*)d_in[8];
  const float* lcW = (const float*)d_in[9];
  const float* lcb = (const float*)d_in[10];
  const float* lvW = (const float*)d_in[11];
  const float* lvb = (const float*)d_in[12];
  const float* gcW = (const float*)d_in[13];
  const float* gcb = (const float*)d_in[14];
  const float* gvW = (const float*)d_in[15];
  const float* gvb = (const float*)d_in[16];
  const float* sw1 = (const float*)d_in[17];
  const float* sw2 = (const float*)d_in[18];
  float* out = (float*)d_out;                    // f32: [a (16*512*512) | sattw (48)]

  const long LD = (long)LL * DD;                 // 262144
  const long DDDD = (long)DD * DD;               // 262144
  float* ws = (float*)d_ws;
  float* xbuf = ws;                              // B*N*L*D = 12582912 floats
  float* scratch = xbuf + (long)BB * NSEG * LD;  // 12582912 (h1; later mk|ct)
  float* mkbuf = scratch;                        // B*L*D
  float* ctbuf = scratch + (long)BB * LD;        // B*L*2D
  float* h2buf = scratch + (long)BB * NSEG * LD; // B*N*D
  float* alphabuf = h2buf + (long)BB * NSEG * DD;// B*N
  // global-stage overlay (xbuf/scratch dead after mix): S | mkc | ctc
  float* Sbuf = ws;                              // 8*8*512*512 = 16777216 floats
  float* mkc  = ws + 16777216;                   // 8*512*512  =  2097152
  float* ctc  = mkc + 2097152;                   // 8*512*1024 =  4194304 (tot 23068672)

  dim3 g88(8, 8, BB), g168(16, 8, BB), blk(256);

  // hyper path
  h2_kernel<<<BB * NSEG, 256, 0, stream>>>(se, w2, b2, h2buf);
  for (int n = 0; n < NSEG; ++n)
    gemm_bias_act<<<g88, blk, 0, stream>>>(seg, w1 + (long)n * DDDD, b1 + n * DD,
                                           scratch + n * LD, DD, DD, LD, NSEG * LD, 1);
  mult_kernel<<<12288, 256, 0, stream>>>(scratch, h2buf);
  for (int n = 0; n < NSEG; ++n)
    gemm_bias_act<<<g88, blk, 0, stream>>>(scratch + n * LD, w3 + (long)n * DDDD, b3 + n * DD,
                                           xbuf + n * LD, DD, DD, NSEG * LD, NSEG * LD, 1);

  // local NL blocks (per n, 2 steps each)
  for (int n = 0; n < NSEG; ++n)
    for (int s = 0; s < 2; ++s) {
      const float* vWp = lvW + (long)(n * 2 + s) * DDDD;
      const float* vbp = lvb + (long)(n * 2 + s) * DD;
      const float* cWp = lcW + (long)(n * 2 + s) * 2 * DDDD;
      const float* cbp = lcb + (long)(n * 2 + s) * 2 * DD;
      gemm_bias_act<<<g88, blk, 0, stream>>>(xbuf + n * LD, vWp, vbp, mkbuf,
                                             DD, DD, NSEG * LD, LD, 0);
      gemm_bias_act<<<g168, blk, 0, stream>>>(xbuf + n * LD, cWp, cbp, ctbuf,
                                              2 * DD, DD, NSEG * LD, 2 * LD, 0);
      local_attn<<<dim3(LL, BB), 512, 0, stream>>>(xbuf + n * LD, mkbuf, ctbuf, msk,
                                                   (long)NSEG * LD);
    }

  // segment attention mix -> a into d_out, sattw into d_out+4194304
  alpha_kernel<<<BB * NSEG, 256, 0, stream>>>(se, sw1, sw2, alphabuf);
  mix_kernel<<<dim3(LL, BB), 128, 0, stream>>>(xbuf, alphabuf, out, out + 4194304);

  // global NL blocks: per 8-batch chunk, score-GEMM / softmax / PV-GEMM
  const int CHB = 8;
  for (int c = 0; c < BB / CHB; ++c) {
    const int b0 = c * CHB;
    float* outc = out + (long)b0 * LD;
    for (int s = 0; s < 2; ++s) {
      gemm_bias_act<<<dim3(8, 8, CHB), blk, 0, stream>>>(
          outc, gvW + (long)s * DDDD, gvb + (long)s * DD, mkc, DD, DD, LD, LD, 0);
      gemm_bias_act<<<dim3(16, 8, CHB), blk, 0, stream>>>(
          outc, gcW + (long)s * 2 * DDDD, gcb + (long)s * 2 * DD, ctc,
          2 * DD, DD, LD, 2 * LD, 0);
      score_kernel<<<dim3(8, 8, CHB * NH), blk, 0, stream>>>(mkc, ctc, msk, Sbuf, b0);
      smax_kernel<<<CHB * NH * LL / 4, 256, 0, stream>>>(Sbuf);
      pv_kernel<<<dim3(8, CHB * NH), blk, 0, stream>>>(Sbuf, ctc, out, b0);
    }
  }
}

// Round 9
// 1766.277 us; speedup vs baseline: 3.6904x; 1.5970x over previous
//
#include <hip/hip_runtime.h>
#include <hip/hip_bf16.h>

#define BB 16
#define LL 512
#define DD 512
#define NSEG 3
#define NH 8
#define DH 64
#define AH 256

typedef __attribute__((ext_vector_type(4))) float f32x4;
typedef __attribute__((ext_vector_type(8))) short s16x8;

__device__ __forceinline__ unsigned short f2b(float f) {
  union { float f; unsigned u; } c; c.f = f;
  unsigned r = (c.u + 0x7FFF + ((c.u >> 16) & 1)) >> 16;   // RNE (no NaN in data)
  return (unsigned short)r;
}

// ---------------- MFMA bf16 GEMM: C = act(A @ W + bias) ----------------
// A: (z) M x K f32 row-major, W: K x Nc f32 row-major, C: M x Nc f32.
// grid (Nc/64, M/64, z), block 256 (4 waves). K multiple of 32.
#define PADK 40   // bf16 per LDS row (32 data + 8 pad) -> 80B rows, b128-aligned
__global__ __launch_bounds__(256) void mfma_gemm(
    const float* __restrict__ A, const float* __restrict__ W,
    const float* __restrict__ bias, float* __restrict__ C,
    int Nc, int K, long bsA, long bsC, int act)
{
  __shared__ unsigned short As[64 * PADK];   // [row][k]
  __shared__ unsigned short Bs[64 * PADK];   // [col][k] (W transposed)
  const int tid = threadIdx.x;
  const int lane = tid & 63, wv = tid >> 6;
  const float* Ab = A + (long)blockIdx.z * bsA + (long)blockIdx.y * 64 * K;
  const float* Wb = W + blockIdx.x * 64;
  float* Cb = C + (long)blockIdx.z * bsC + (long)blockIdx.y * 64 * Nc + blockIdx.x * 64;

  const int arow = tid >> 2, akq = tid & 3;        // A staging: row, k-octet
  const int bkp = tid & 15, bnq = tid >> 4;        // B staging: k-pair, n-quad
  const int fr = lane & 15, fk = (lane >> 4) * 8;  // fragment row/col + k offset

  f32x4 acc[4] = {};
  for (int k0 = 0; k0 < K; k0 += 32) {
    // ---- stage A: 8 bf16 per thread, one b128 write ----
    {
      const float* ap = Ab + (long)arow * K + k0 + akq * 8;
      float4 a0 = *(const float4*)ap;
      float4 a1 = *(const float4*)(ap + 4);
      union { unsigned short h[8]; uint4 v; } u;
      u.h[0] = f2b(a0.x); u.h[1] = f2b(a0.y); u.h[2] = f2b(a0.z); u.h[3] = f2b(a0.w);
      u.h[4] = f2b(a1.x); u.h[5] = f2b(a1.y); u.h[6] = f2b(a1.z); u.h[7] = f2b(a1.w);
      *(uint4*)&As[arow * PADK + akq * 8] = u.v;
    }
    // ---- stage B transposed: W[k][n] -> Bs[n][k]; 2 k's x 4 n's per thread ----
    {
      const float* wp = Wb + (long)(k0 + 2 * bkp) * Nc + 4 * bnq;
      float4 w0 = *(const float4*)wp;
      float4 w1 = *(const float4*)(wp + Nc);
      unsigned* bsw = (unsigned*)Bs;
      bsw[(4 * bnq + 0) * (PADK / 2) + bkp] = (unsigned)f2b(w0.x) | ((unsigned)f2b(w1.x) << 16);
      bsw[(4 * bnq + 1) * (PADK / 2) + bkp] = (unsigned)f2b(w0.y) | ((unsigned)f2b(w1.y) << 16);
      bsw[(4 * bnq + 2) * (PADK / 2) + bkp] = (unsigned)f2b(w0.z) | ((unsigned)f2b(w1.z) << 16);
      bsw[(4 * bnq + 3) * (PADK / 2) + bkp] = (unsigned)f2b(w0.w) | ((unsigned)f2b(w1.w) << 16);
    }
    __syncthreads();
    s16x8 af = *(const s16x8*)&As[(wv * 16 + fr) * PADK + fk];
#pragma unroll
    for (int nt = 0; nt < 4; ++nt) {
      s16x8 bf = *(const s16x8*)&Bs[(nt * 16 + fr) * PADK + fk];
      acc[nt] = __builtin_amdgcn_mfma_f32_16x16x32_bf16(af, bf, acc[nt], 0, 0, 0);
    }
    __syncthreads();
  }
  // ---- epilogue: D lane mapping col=lane&15, row=(lane>>4)*4+reg ----
  const int rowb = wv * 16 + (lane >> 4) * 4;
  const int colb = lane & 15;
#pragma unroll
  for (int nt = 0; nt < 4; ++nt) {
    const float bv = bias[blockIdx.x * 64 + nt * 16 + colb];
#pragma unroll
    for (int j = 0; j < 4; ++j) {
      float v = acc[nt][j] + bv;
      if (act) v = fmaxf(v, 0.f);
      Cb[(long)(rowb + j) * Nc + nt * 16 + colb] = v;
    }
  }
}

// ---------------- h2 = relu(se @ w2[n] + b2[n]) ----------------
__global__ __launch_bounds__(256) void h2_kernel(
    const float* __restrict__ se, const float* __restrict__ w2,
    const float* __restrict__ b2, float* __restrict__ h2)
{
  __shared__ float ses[DD];
  const int bn = blockIdx.x;          // b*NSEG + n
  const int n = bn % NSEG;
  const int t = threadIdx.x;
  ses[t] = se[(long)bn * DD + t];
  ses[t + 256] = se[(long)bn * DD + t + 256];
  __syncthreads();
  const float* wn = w2 + (long)n * DD * DD;
  for (int j = t; j < DD; j += 256) {
    float acc = b2[n * DD + j];
    for (int k = 0; k < DD; ++k) acc = fmaf(ses[k], wn[(long)k * DD + j], acc);
    h2[(long)bn * DD + j] = fmaxf(acc, 0.f);
  }
}

// ---------------- h1 *= h2 (broadcast over l) ----------------
__global__ __launch_bounds__(256) void mult_kernel(float* __restrict__ h1,
                                                   const float* __restrict__ h2)
{
  long i4 = (long)blockIdx.x * 256 + threadIdx.x;   // float4 index; total 3145728
  float4 v = ((float4*)h1)[i4];
  long bn = i4 >> 16;       // / (L*D/4)
  int d4 = (int)(i4 & 127); // % (D/4)
  float4 m = ((const float4*)h2)[bn * 128 + d4];
  v.x *= m.x; v.y *= m.y; v.z *= m.z; v.w *= m.w;
  ((float4*)h1)[i4] = v;
}

// ---------------- local banded attention, in-place residual ----------------
__global__ __launch_bounds__(512) void local_attn(
    float* __restrict__ x, const float* __restrict__ mk,
    const float* __restrict__ ct, const float* __restrict__ mask, long bsX)
{
  const int l = blockIdx.x, b = blockIdx.y;
  const int t = threadIdx.x;
  const int h = t >> 6, d = t & 63;
  const float mkv = mk[((long)b * LL + l) * DD + h * DH + d];
  const float* ctb = ct + (long)b * LL * (2 * DD);
  const float* mb = mask + (long)b * LL;
  float sc[15];
#pragma unroll
  for (int i = 0; i < 15; ++i) {
    int m = l - 7 + i;
    bool valid = (m >= 0) && (m < LL);
    int mc = valid ? m : 0;
    float p = mkv * ctb[(long)mc * (2 * DD) + h * DH + d];
#pragma unroll
    for (int o = 32; o > 0; o >>= 1) p += __shfl_xor(p, o, 64);
    float s = p * 0.125f;
    if (mb[mc] == 0.f) s = -1e9f;
    sc[i] = valid ? s : -3e9f;
  }
  float mx = sc[0];
#pragma unroll
  for (int i = 1; i < 15; ++i) mx = fmaxf(mx, sc[i]);
  float sum = 0.f;
#pragma unroll
  for (int i = 0; i < 15; ++i) { sc[i] = __expf(sc[i] - mx); sum += sc[i]; }
  const float inv = 1.f / sum;
  float r = 0.f;
#pragma unroll
  for (int i = 0; i < 15; ++i) {
    int m = l - 7 + i;
    int mc = (m < 0) ? 0 : ((m >= LL) ? (LL - 1) : m);
    r = fmaf(sc[i], ctb[(long)mc * (2 * DD) + DD + h * DH + d], r);
  }
  x[(long)b * bsX + (long)l * DD + h * DH + d] += r * inv;
}

// ---------------- global attention: phase 1, scores ----------------
__global__ __launch_bounds__(256) void score_kernel(
    const float* __restrict__ mk, const float* __restrict__ ct,
    const float* __restrict__ msk, float* __restrict__ S, int b0)
{
  __shared__ float As[64][65];   // mk^T: As[d][l]
  __shared__ float Bs[64][65];   // mq^T: Bs[d][m]
  const int bz = blockIdx.z;     // chunk-local b*8 + h
  const int bl = bz >> 3, h = bz & 7;
  const int t = threadIdx.x;
  const float* Ab = mk + ((long)bl * LL + blockIdx.y * 64) * DD + h * DH;
  const float* Bb = ct + ((long)bl * LL + blockIdx.x * 64) * (2 * DD) + h * DH;
  {
    int r = t >> 2, c0 = (t & 3) << 4;
#pragma unroll
    for (int i = 0; i < 4; ++i) {
      int c = c0 + i * 4;
      float4 a = *(const float4*)(Ab + (long)r * DD + c);
      As[c][r] = a.x; As[c + 1][r] = a.y; As[c + 2][r] = a.z; As[c + 3][r] = a.w;
      float4 q = *(const float4*)(Bb + (long)r * (2 * DD) + c);
      Bs[c][r] = q.x; Bs[c + 1][r] = q.y; Bs[c + 2][r] = q.z; Bs[c + 3][r] = q.w;
    }
  }
  __syncthreads();
  const int tx = t & 15, ty = t >> 4;
  float acc[4][4] = {};
#pragma unroll 8
  for (int d = 0; d < 64; ++d) {
    float a4[4], b4[4];
#pragma unroll
    for (int i = 0; i < 4; ++i) { a4[i] = As[d][(ty << 2) + i]; b4[i] = Bs[d][(tx << 2) + i]; }
#pragma unroll
    for (int i = 0; i < 4; ++i)
#pragma unroll
      for (int j = 0; j < 4; ++j) acc[i][j] = fmaf(a4[i], b4[j], acc[i][j]);
  }
  const float* mrow = msk + (long)(b0 + bl) * LL + blockIdx.x * 64 + (tx << 2);
  float mv[4];
#pragma unroll
  for (int j = 0; j < 4; ++j) mv[j] = mrow[j];
  float* Sb = S + ((long)bz * LL + blockIdx.y * 64) * LL + blockIdx.x * 64;
#pragma unroll
  for (int i = 0; i < 4; ++i) {
    float4 o;
    float* op = &o.x;
#pragma unroll
    for (int j = 0; j < 4; ++j)
      op[j] = (mv[j] == 0.f) ? -1e9f : acc[i][j] * 0.125f;
    *(float4*)(Sb + (long)((ty << 2) + i) * LL + (tx << 2)) = o;
  }
}

// ---------------- global attention: phase 2, row softmax (wave per row) ----------------
__global__ __launch_bounds__(256) void smax_kernel(float* __restrict__ S)
{
  const int w = threadIdx.x >> 6, lane = threadIdx.x & 63;
  long row = (long)blockIdx.x * 4 + w;
  float* p = S + row * LL;
  float v[8];
  float mx = -3e38f;
#pragma unroll
  for (int i = 0; i < 8; ++i) { v[i] = p[lane + i * 64]; mx = fmaxf(mx, v[i]); }
#pragma unroll
  for (int o = 32; o > 0; o >>= 1) mx = fmaxf(mx, __shfl_xor(mx, o, 64));
  float sum = 0.f;
#pragma unroll
  for (int i = 0; i < 8; ++i) { v[i] = __expf(v[i] - mx); sum += v[i]; }
#pragma unroll
  for (int o = 32; o > 0; o >>= 1) sum += __shfl_xor(sum, o, 64);
  const float inv = 1.f / sum;
#pragma unroll
  for (int i = 0; i < 8; ++i) p[lane + i * 64] = v[i] * inv;
}

// ---------------- global attention: phase 3, PV + residual ----------------
__global__ __launch_bounds__(256) void pv_kernel(
    const float* __restrict__ S, const float* __restrict__ ct,
    float* __restrict__ out, int b0)
{
  __shared__ float As[32][68];   // S^T tile: As[k][l]
  __shared__ float Bs[32][68];   // V tile:  Bs[k][d]
  const int bz = blockIdx.y;     // chunk-local b*8 + h
  const int bl = bz >> 3, h = bz & 7;
  const float* Ab = S + ((long)bz * LL + blockIdx.x * 64) * LL;
  const float* Bb = ct + (long)bl * LL * (2 * DD) + DD + h * DH;
  float* Cb = out + ((long)(b0 + bl) * LL + blockIdx.x * 64) * DD + h * DH;
  const int tid = threadIdx.x;
  const int tx = tid & 15, ty = tid >> 4;
  float acc[4][4] = {};
  for (int k0 = 0; k0 < LL; k0 += 32) {
#pragma unroll
    for (int i = 0; i < 2; ++i) {
      int idx = tid + i * 256;
      int r = idx >> 3, kc = (idx & 7) << 2;
      float4 av = *(const float4*)(Ab + (long)r * LL + k0 + kc);
      As[kc][r] = av.x; As[kc + 1][r] = av.y; As[kc + 2][r] = av.z; As[kc + 3][r] = av.w;
      int kk = idx >> 4, nc = (idx & 15) << 2;
      float4 bv = *(const float4*)(Bb + (long)(k0 + kk) * (2 * DD) + nc);
      *(float4*)&Bs[kk][nc] = bv;
    }
    __syncthreads();
#pragma unroll
    for (int kk = 0; kk < 32; ++kk) {
      float4 a4 = *(const float4*)&As[kk][ty << 2];
      float4 b4 = *(const float4*)&Bs[kk][tx << 2];
      float av[4] = {a4.x, a4.y, a4.z, a4.w};
      float bv[4] = {b4.x, b4.y, b4.z, b4.w};
#pragma unroll
      for (int i = 0; i < 4; ++i)
#pragma unroll
        for (int j = 0; j < 4; ++j) acc[i][j] = fmaf(av[i], bv[j], acc[i][j]);
    }
    __syncthreads();
  }
#pragma unroll
  for (int i = 0; i < 4; ++i) {
    float* cp = Cb + (long)((ty << 2) + i) * DD + (tx << 2);
    float4 o = *(const float4*)cp;
    o.x += acc[i][0]; o.y += acc[i][1]; o.z += acc[i][2]; o.w += acc[i][3];
    *(float4*)cp = o;
  }
}

// ---------------- alpha = tanh(se @ sw1) @ sw2 ----------------
__global__ __launch_bounds__(256) void alpha_kernel(
    const float* __restrict__ se, const float* __restrict__ w1,
    const float* __restrict__ w2, float* __restrict__ alpha)
{
  __shared__ float ses[DD];
  __shared__ float red[4];
  const int bn = blockIdx.x;
  const int t = threadIdx.x;
  ses[t] = se[(long)bn * DD + t];
  ses[t + 256] = se[(long)bn * DD + t + 256];
  __syncthreads();
  float acc = 0.f;
  for (int k = 0; k < DD; ++k) acc = fmaf(ses[k], w1[(long)k * AH + t], acc);
  float v = tanhf(acc) * w2[t];
#pragma unroll
  for (int o = 32; o > 0; o >>= 1) v += __shfl_xor(v, o, 64);
  if ((t & 63) == 0) red[t >> 6] = v;
  __syncthreads();
  if (t == 0) alpha[bn] = red[0] + red[1] + red[2] + red[3];
}

// ---- a[b][l][:] = sum_n sattw[b,n]*ss[b,n,l,:] -> f32 out; emit sattw f32 ----
__global__ __launch_bounds__(128) void mix_kernel(
    const float* __restrict__ xbuf, const float* __restrict__ alpha,
    float* __restrict__ abuf, float* __restrict__ outw)
{
  const int l = blockIdx.x, b = blockIdx.y;
  const float a0 = alpha[b * 3 + 0], a1 = alpha[b * 3 + 1], a2 = alpha[b * 3 + 2];
  const float mx = fmaxf(a0, fmaxf(a1, a2));
  const float e0 = __expf(a0 - mx), e1 = __expf(a1 - mx), e2 = __expf(a2 - mx);
  const float inv = 1.f / (e0 + e1 + e2);
  const float w0 = e0 * inv, w1 = e1 * inv, w2 = e2 * inv;
  const float4* x0 = (const float4*)(xbuf + (((long)b * 3 + 0) * LL + l) * DD);
  const float4* x1 = (const float4*)(xbuf + (((long)b * 3 + 1) * LL + l) * DD);
  const float4* x2 = (const float4*)(xbuf + (((long)b * 3 + 2) * LL + l) * DD);
  float4* ar = (float4*)(abuf + ((long)b * LL + l) * DD);
  const int t = threadIdx.x;
  float4 v0 = x0[t], v1 = x1[t], v2 = x2[t];
  float4 o;
  o.x = w0 * v0.x + w1 * v1.x + w2 * v2.x;
  o.y = w0 * v0.y + w1 * v1.y + w2 * v2.y;
  o.z = w0 * v0.z + w1 * v1.z + w2 * v2.z;
  o.w = w0 * v0.w + w1 * v1.w + w2 * v2.w;
  ar[t] = o;
  if (l == 0 && t < 3) {
    float wv = (t == 0) ? w0 : ((t == 1) ? w1 : w2);
    outw[b * 3 + t] = wv;
  }
}

extern "C" void kernel_launch(void* const* d_in, const int* in_sizes, int n_in,
                              void* d_out, int out_size, void* d_ws, size_t ws_size,
                              hipStream_t stream) {
  const float* seg = (const float*)d_in[0];
  const float* msk = (const float*)d_in[1];
  const float* se  = (const float*)d_in[2];
  const float* w1  = (const float*)d_in[3];
  const float* b1  = (const float*)d_in[4];
  const float* w2  = (const float*)d_in[5];
  const float* b2  = (const float*)d_in[6];
  const float* w3  = (const float*)d_in[7];
  const float* b3  = (const float*)d_in[8];
  const float* lcW = (const float*)d_in[9];
  const float* lcb = (const float*)d_in[10];
  const float* lvW = (const float*)d_in[11];
  const float* lvb = (const float*)d_in[12];
  const float* gcW = (const float*)d_in[13];
  const float* gcb = (const float*)d_in[14];
  const float* gvW = (const float*)d_in[15];
  const float* gvb = (const float*)d_in[16];
  const float* sw1 = (const float*)d_in[17];
  const float* sw2 = (const float*)d_in[18];
  float* out = (float*)d_out;                    // f32: [a (16*512*512) | sattw (48)]

  const long LD = (long)LL * DD;                 // 262144
  const long DDDD = (long)DD * DD;               // 262144
  float* ws = (float*)d_ws;
  float* xbuf = ws;                              // B*N*L*D = 12582912 floats
  float* scratch = xbuf + (long)BB * NSEG * LD;  // 12582912 (h1; later mk|ct)
  float* mkbuf = scratch;                        // B*L*D
  float* ctbuf = scratch + (long)BB * LD;        // B*L*2D
  float* h2buf = scratch + (long)BB * NSEG * LD; // B*N*D
  float* alphabuf = h2buf + (long)BB * NSEG * DD;// B*N
  // global-stage overlay (xbuf/scratch dead after mix): S | mkc | ctc
  float* Sbuf = ws;                              // 8*8*512*512 = 16777216 floats
  float* mkc  = ws + 16777216;                   // 8*512*512  =  2097152
  float* ctc  = mkc + 2097152;                   // 8*512*1024 =  4194304 (tot 23068672)

  dim3 g88(8, 8, BB), g168(16, 8, BB), blk(256);

  // hyper path
  h2_kernel<<<BB * NSEG, 256, 0, stream>>>(se, w2, b2, h2buf);
  for (int n = 0; n < NSEG; ++n)
    mfma_gemm<<<g88, blk, 0, stream>>>(seg, w1 + (long)n * DDDD, b1 + n * DD,
                                       scratch + n * LD, DD, DD, LD, NSEG * LD, 1);
  mult_kernel<<<12288, 256, 0, stream>>>(scratch, h2buf);
  for (int n = 0; n < NSEG; ++n)
    mfma_gemm<<<g88, blk, 0, stream>>>(scratch + n * LD, w3 + (long)n * DDDD, b3 + n * DD,
                                       xbuf + n * LD, DD, DD, NSEG * LD, NSEG * LD, 1);

  // local NL blocks (per n, 2 steps each)
  for (int n = 0; n < NSEG; ++n)
    for (int s = 0; s < 2; ++s) {
      const float* vWp = lvW + (long)(n * 2 + s) * DDDD;
      const float* vbp = lvb + (long)(n * 2 + s) * DD;
      const float* cWp = lcW + (long)(n * 2 + s) * 2 * DDDD;
      const float* cbp = lcb + (long)(n * 2 + s) * 2 * DD;
      mfma_gemm<<<g88, blk, 0, stream>>>(xbuf + n * LD, vWp, vbp, mkbuf,
                                         DD, DD, NSEG * LD, LD, 0);
      mfma_gemm<<<g168, blk, 0, stream>>>(xbuf + n * LD, cWp, cbp, ctbuf,
                                          2 * DD, DD, NSEG * LD, 2 * LD, 0);
      local_attn<<<dim3(LL, BB), 512, 0, stream>>>(xbuf + n * LD, mkbuf, ctbuf, msk,
                                                   (long)NSEG * LD);
    }

  // segment attention mix -> a into d_out, sattw into d_out+4194304
  alpha_kernel<<<BB * NSEG, 256, 0, stream>>>(se, sw1, sw2, alphabuf);
  mix_kernel<<<dim3(LL, BB), 128, 0, stream>>>(xbuf, alphabuf, out, out + 4194304);

  // global NL blocks: per 8-batch chunk, score-GEMM / softmax / PV-GEMM
  const int CHB = 8;
  for (int c = 0; c < BB / CHB; ++c) {
    const int b0 = c * CHB;
    float* outc = out + (long)b0 * LD;
    for (int s = 0; s < 2; ++s) {
      mfma_gemm<<<dim3(8, 8, CHB), blk, 0, stream>>>(
          outc, gvW + (long)s * DDDD, gvb + (long)s * DD, mkc, DD, DD, LD, LD, 0);
      mfma_gemm<<<dim3(16, 8, CHB), blk, 0, stream>>>(
          outc, gcW + (long)s * 2 * DDDD, gcb + (long)s * 2 * DD, ctc,
          2 * DD, DD, LD, 2 * LD, 0);
      score_kernel<<<dim3(8, 8, CHB * NH), blk, 0, stream>>>(mkc, ctc, msk, Sbuf, b0);
      smax_kernel<<<CHB * NH * LL / 4, 256, 0, stream>>>(Sbuf);
      pv_kernel<<<dim3(8, CHB * NH), blk, 0, stream>>>(Sbuf, ctc, out, b0);
    }
  }
}

// Round 11
// 1594.355 us; speedup vs baseline: 4.0883x; 1.1078x over previous
//
#include <hip/hip_runtime.h>
#include <hip/hip_bf16.h>

#define BB 16
#define LL 512
#define DD 512
#define NSEG 3
#define NH 8
#define DH 64
#define AH 256

typedef __attribute__((ext_vector_type(4))) float f32x4;
typedef __attribute__((ext_vector_type(8))) short s16x8;
typedef unsigned short ushort_t;

__device__ __forceinline__ unsigned short f2b(float f) {
  union { float f; unsigned u; } c; c.f = f;
  unsigned r = (c.u + 0x7FFF + ((c.u >> 16) & 1)) >> 16;   // RNE (no NaN in data)
  return (unsigned short)r;
}

// ---------------- f32 -> bf16 cast, 8 elems/thread; batched-stride form ----------------
// idx8 = global thread; b = idx8>>shift selects batch (src + b*bstride), r8 inside.
__global__ __launch_bounds__(256) void castb(
    const float* __restrict__ src, long bstride, int shift,
    ushort_t* __restrict__ dst)
{
  long idx8 = (long)blockIdx.x * 256 + threadIdx.x;
  long b = idx8 >> shift;
  long r8 = idx8 & ((1L << shift) - 1);
  const float* p = src + b * bstride + r8 * 8;
  float4 a = *(const float4*)p;
  float4 c = *(const float4*)(p + 4);
  union { ushort_t h[8]; uint4 v; } u;
  u.h[0] = f2b(a.x); u.h[1] = f2b(a.y); u.h[2] = f2b(a.z); u.h[3] = f2b(a.w);
  u.h[4] = f2b(c.x); u.h[5] = f2b(c.y); u.h[6] = f2b(c.z); u.h[7] = f2b(c.w);
  *(uint4*)(dst + idx8 * 8) = u.v;
}

// ---------------- (h1 * h2) -> bf16, per n plane ----------------
// src strided [b][3][l][d] (base at n), h2 row (b*3+n); dst dense [b][l][d] bf16
__global__ __launch_bounds__(256) void mult_cast(
    const float* __restrict__ h1, const float* __restrict__ h2, int n,
    ushort_t* __restrict__ dst)
{
  long idx8 = (long)blockIdx.x * 256 + threadIdx.x;   // 524288 total
  long b = idx8 >> 15;
  long r8 = idx8 & 32767;
  int d0 = (int)(r8 & 63) * 8;
  const float* p = h1 + b * (3 * (long)LL * DD) + r8 * 8;
  const float* q = h2 + (b * 3 + n) * DD + d0;
  float4 a = *(const float4*)p;
  float4 c = *(const float4*)(p + 4);
  float4 m0 = *(const float4*)q;
  float4 m1 = *(const float4*)(q + 4);
  union { ushort_t h[8]; uint4 v; } u;
  u.h[0] = f2b(a.x * m0.x); u.h[1] = f2b(a.y * m0.y);
  u.h[2] = f2b(a.z * m0.z); u.h[3] = f2b(a.w * m0.w);
  u.h[4] = f2b(c.x * m1.x); u.h[5] = f2b(c.y * m1.y);
  u.h[6] = f2b(c.z * m1.z); u.h[7] = f2b(c.w * m1.w);
  *(uint4*)(dst + idx8 * 8) = u.v;
}

// ---------------- MFMA bf16 GEMM: C = act(A @ W + bias) ----------------
// A: (z) M x K bf16 row-major, W: K x Nc bf16 row-major, C: M x Nc f32.
// grid (Nc/64, M/64, z), block 256 (4 waves). K multiple of 32.
#define PADK 40
__global__ __launch_bounds__(256) void mfma_gemm(
    const ushort_t* __restrict__ A, const ushort_t* __restrict__ W,
    const float* __restrict__ bias, float* __restrict__ C,
    int Nc, int K, long bsA, long bsC, int act)
{
  __shared__ ushort_t As[64 * PADK];   // [row][k]
  __shared__ ushort_t Bs[64 * PADK];   // [col][k] (W transposed)
  const int tid = threadIdx.x;
  const int lane = tid & 63, wv = tid >> 6;
  const ushort_t* Ab = A + (long)blockIdx.z * bsA + (long)blockIdx.y * 64 * K;
  const ushort_t* Wb = W + blockIdx.x * 64;
  float* Cb = C + (long)blockIdx.z * bsC + (long)blockIdx.y * 64 * Nc + blockIdx.x * 64;

  const int arow = tid >> 2, akq = tid & 3;        // A staging
  const int bkp = tid & 15, bnq = tid >> 4;        // B staging
  const int fr = lane & 15, fk = (lane >> 4) * 8;  // fragment row + k offset

  f32x4 acc[4] = {};
  for (int k0 = 0; k0 < K; k0 += 32) {
    // A: 8 bf16 per thread, one b128 copy
    *(uint4*)&As[arow * PADK + akq * 8] =
        *(const uint4*)(Ab + (long)arow * K + k0 + akq * 8);
    // B transposed: rows k0+2bkp, k0+2bkp+1; 4 n's starting 4*bnq
    {
      const ushort_t* wp = Wb + (long)(k0 + 2 * bkp) * Nc + 4 * bnq;
      ushort4 w0 = *(const ushort4*)wp;
      ushort4 w1 = *(const ushort4*)(wp + Nc);
      unsigned* bsw = (unsigned*)Bs;
      bsw[(4 * bnq + 0) * (PADK / 2) + bkp] = (unsigned)w0.x | ((unsigned)w1.x << 16);
      bsw[(4 * bnq + 1) * (PADK / 2) + bkp] = (unsigned)w0.y | ((unsigned)w1.y << 16);
      bsw[(4 * bnq + 2) * (PADK / 2) + bkp] = (unsigned)w0.z | ((unsigned)w1.z << 16);
      bsw[(4 * bnq + 3) * (PADK / 2) + bkp] = (unsigned)w0.w | ((unsigned)w1.w << 16);
    }
    __syncthreads();
    s16x8 af = *(const s16x8*)&As[(wv * 16 + fr) * PADK + fk];
#pragma unroll
    for (int nt = 0; nt < 4; ++nt) {
      s16x8 bf = *(const s16x8*)&Bs[(nt * 16 + fr) * PADK + fk];
      acc[nt] = __builtin_amdgcn_mfma_f32_16x16x32_bf16(af, bf, acc[nt], 0, 0, 0);
    }
    __syncthreads();
  }
  const int rowb = wv * 16 + (lane >> 4) * 4;
  const int colb = lane & 15;
#pragma unroll
  for (int nt = 0; nt < 4; ++nt) {
    const float bv = bias[blockIdx.x * 64 + nt * 16 + colb];
#pragma unroll
    for (int j = 0; j < 4; ++j) {
      float v = acc[nt][j] + bv;
      if (act) v = fmaxf(v, 0.f);
      Cb[(long)(rowb + j) * Nc + nt * 16 + colb] = v;
    }
  }
}

// ---------------- h2 = relu(se @ w2[n] + b2[n]) ----------------
__global__ __launch_bounds__(256) void h2_kernel(
    const float* __restrict__ se, const float* __restrict__ w2,
    const float* __restrict__ b2, float* __restrict__ h2)
{
  __shared__ float ses[DD];
  const int bn = blockIdx.x;          // b*NSEG + n
  const int n = bn % NSEG;
  const int t = threadIdx.x;
  ses[t] = se[(long)bn * DD + t];
  ses[t + 256] = se[(long)bn * DD + t + 256];
  __syncthreads();
  const float* wn = w2 + (long)n * DD * DD;
  for (int j = t; j < DD; j += 256) {
    float acc = b2[n * DD + j];
    for (int k = 0; k < DD; ++k) acc = fmaf(ses[k], wn[(long)k * DD + j], acc);
    h2[(long)bn * DD + j] = fmaxf(acc, 0.f);
  }
}

// ---------------- local banded attention v2: group-parallel dots ----------------
// block 512 = 8 waves (wave per head); grid (L, B)
__global__ __launch_bounds__(512) void local_attn(
    float* __restrict__ x, const float* __restrict__ mk,
    const float* __restrict__ ct, const float* __restrict__ mask, long bsX)
{
  const int l = blockIdx.x, b = blockIdx.y;
  const int t = threadIdx.x;
  const int h = t >> 6, lane = t & 63;
  const int grp = lane >> 2, r4 = lane & 3;      // 16 groups x 4 lanes
  const float* ctb = ct + (long)b * LL * (2 * DD);
  const float* mb = mask + (long)b * LL;
  // phase 1: group grp computes score for neighbor l-7+grp (grp<15)
  int m = l - 7 + grp;
  bool valid = (grp < 15) && (m >= 0) && (m < LL);
  int mc = valid ? m : 0;
  const float* mkp = mk + ((long)b * LL + l) * DD + h * DH + r4 * 16;
  const float* mqp = ctb + (long)mc * (2 * DD) + h * DH + r4 * 16;
  float dot = 0.f;
#pragma unroll
  for (int j = 0; j < 16; j += 4) {
    float4 a = *(const float4*)(mkp + j);
    float4 q = *(const float4*)(mqp + j);
    dot = fmaf(a.x, q.x, fmaf(a.y, q.y, fmaf(a.z, q.z, fmaf(a.w, q.w, dot))));
  }
  dot += __shfl_xor(dot, 1, 64);
  dot += __shfl_xor(dot, 2, 64);
  float s = dot * 0.125f;
  if (mb[mc] == 0.f) s = -1e9f;
  if (!valid) s = -3e9f;
  // broadcast all 15 scores to every lane
  float sc[15];
#pragma unroll
  for (int i = 0; i < 15; ++i) sc[i] = __shfl(s, i * 4, 64);
  float mx = sc[0];
#pragma unroll
  for (int i = 1; i < 15; ++i) mx = fmaxf(mx, sc[i]);
  float sum = 0.f;
#pragma unroll
  for (int i = 0; i < 15; ++i) { sc[i] = __expf(sc[i] - mx); sum += sc[i]; }
  const float inv = 1.f / sum;
  // phase 2: PV, lane = d
  float r = 0.f;
#pragma unroll
  for (int i = 0; i < 15; ++i) {
    int mm = l - 7 + i;
    int mcc = (mm < 0) ? 0 : ((mm >= LL) ? (LL - 1) : mm);
    r = fmaf(sc[i], ctb[(long)mcc * (2 * DD) + DD + h * DH + lane], r);
  }
  x[(long)b * bsX + (long)l * DD + h * DH + lane] += r * inv;
}

// ---------------- global attention: phase 1, scores ----------------
__global__ __launch_bounds__(256) void score_kernel(
    const float* __restrict__ mk, const float* __restrict__ ct,
    const float* __restrict__ msk, float* __restrict__ S, int b0)
{
  __shared__ float As[64][65];   // mk^T: As[d][l]
  __shared__ float Bs[64][65];   // mq^T: Bs[d][m]
  const int bz = blockIdx.z;     // chunk-local b*8 + h
  const int bl = bz >> 3, h = bz & 7;
  const int t = threadIdx.x;
  const float* Ab = mk + ((long)bl * LL + blockIdx.y * 64) * DD + h * DH;
  const float* Bb = ct + ((long)bl * LL + blockIdx.x * 64) * (2 * DD) + h * DH;
  {
    int r = t >> 2, c0 = (t & 3) << 4;
#pragma unroll
    for (int i = 0; i < 4; ++i) {
      int c = c0 + i * 4;
      float4 a = *(const float4*)(Ab + (long)r * DD + c);
      As[c][r] = a.x; As[c + 1][r] = a.y; As[c + 2][r] = a.z; As[c + 3][r] = a.w;
      float4 q = *(const float4*)(Bb + (long)r * (2 * DD) + c);
      Bs[c][r] = q.x; Bs[c + 1][r] = q.y; Bs[c + 2][r] = q.z; Bs[c + 3][r] = q.w;
    }
  }
  __syncthreads();
  const int tx = t & 15, ty = t >> 4;
  float acc[4][4] = {};
#pragma unroll 8
  for (int d = 0; d < 64; ++d) {
    float a4[4], b4[4];
#pragma unroll
    for (int i = 0; i < 4; ++i) { a4[i] = As[d][(ty << 2) + i]; b4[i] = Bs[d][(tx << 2) + i]; }
#pragma unroll
    for (int i = 0; i < 4; ++i)
#pragma unroll
      for (int j = 0; j < 4; ++j) acc[i][j] = fmaf(a4[i], b4[j], acc[i][j]);
  }
  const float* mrow = msk + (long)(b0 + bl) * LL + blockIdx.x * 64 + (tx << 2);
  float mv[4];
#pragma unroll
  for (int j = 0; j < 4; ++j) mv[j] = mrow[j];
  float* Sb = S + ((long)bz * LL + blockIdx.y * 64) * LL + blockIdx.x * 64;
#pragma unroll
  for (int i = 0; i < 4; ++i) {
    float4 o;
    float* op = &o.x;
#pragma unroll
    for (int j = 0; j < 4; ++j)
      op[j] = (mv[j] == 0.f) ? -1e9f : acc[i][j] * 0.125f;
    *(float4*)(Sb + (long)((ty << 2) + i) * LL + (tx << 2)) = o;
  }
}

// ---------------- global attention: phase 2, row softmax ----------------
__global__ __launch_bounds__(256) void smax_kernel(float* __restrict__ S)
{
  const int w = threadIdx.x >> 6, lane = threadIdx.x & 63;
  long row = (long)blockIdx.x * 4 + w;
  float* p = S + row * LL;
  float v[8];
  float mx = -3e38f;
#pragma unroll
  for (int i = 0; i < 8; ++i) { v[i] = p[lane + i * 64]; mx = fmaxf(mx, v[i]); }
#pragma unroll
  for (int o = 32; o > 0; o >>= 1) mx = fmaxf(mx, __shfl_xor(mx, o, 64));
  float sum = 0.f;
#pragma unroll
  for (int i = 0; i < 8; ++i) { v[i] = __expf(v[i] - mx); sum += v[i]; }
#pragma unroll
  for (int o = 32; o > 0; o >>= 1) sum += __shfl_xor(sum, o, 64);
  const float inv = 1.f / sum;
#pragma unroll
  for (int i = 0; i < 8; ++i) p[lane + i * 64] = v[i] * inv;
}

// ---------------- global attention: phase 3, PV + residual ----------------
__global__ __launch_bounds__(256) void pv_kernel(
    const float* __restrict__ S, const float* __restrict__ ct,
    float* __restrict__ out, int b0)
{
  __shared__ float As[32][68];
  __shared__ float Bs[32][68];
  const int bz = blockIdx.y;
  const int bl = bz >> 3, h = bz & 7;
  const float* Ab = S + ((long)bz * LL + blockIdx.x * 64) * LL;
  const float* Bb = ct + (long)bl * LL * (2 * DD) + DD + h * DH;
  float* Cb = out + ((long)(b0 + bl) * LL + blockIdx.x * 64) * DD + h * DH;
  const int tid = threadIdx.x;
  const int tx = tid & 15, ty = tid >> 4;
  float acc[4][4] = {};
  for (int k0 = 0; k0 < LL; k0 += 32) {
#pragma unroll
    for (int i = 0; i < 2; ++i) {
      int idx = tid + i * 256;
      int r = idx >> 3, kc = (idx & 7) << 2;
      float4 av = *(const float4*)(Ab + (long)r * LL + k0 + kc);
      As[kc][r] = av.x; As[kc + 1][r] = av.y; As[kc + 2][r] = av.z; As[kc + 3][r] = av.w;
      int kk = idx >> 4, nc = (idx & 15) << 2;
      float4 bv = *(const float4*)(Bb + (long)(k0 + kk) * (2 * DD) + nc);
      *(float4*)&Bs[kk][nc] = bv;
    }
    __syncthreads();
#pragma unroll
    for (int kk = 0; kk < 32; ++kk) {
      float4 a4 = *(const float4*)&As[kk][ty << 2];
      float4 b4 = *(const float4*)&Bs[kk][tx << 2];
      float av[4] = {a4.x, a4.y, a4.z, a4.w};
      float bv[4] = {b4.x, b4.y, b4.z, b4.w};
#pragma unroll
      for (int i = 0; i < 4; ++i)
#pragma unroll
        for (int j = 0; j < 4; ++j) acc[i][j] = fmaf(av[i], bv[j], acc[i][j]);
    }
    __syncthreads();
  }
#pragma unroll
  for (int i = 0; i < 4; ++i) {
    float* cp = Cb + (long)((ty << 2) + i) * DD + (tx << 2);
    float4 o = *(const float4*)cp;
    o.x += acc[i][0]; o.y += acc[i][1]; o.z += acc[i][2]; o.w += acc[i][3];
    *(float4*)cp = o;
  }
}

// ---------------- alpha = tanh(se @ sw1) @ sw2 ----------------
__global__ __launch_bounds__(256) void alpha_kernel(
    const float* __restrict__ se, const float* __restrict__ w1,
    const float* __restrict__ w2, float* __restrict__ alpha)
{
  __shared__ float ses[DD];
  __shared__ float red[4];
  const int bn = blockIdx.x;
  const int t = threadIdx.x;
  ses[t] = se[(long)bn * DD + t];
  ses[t + 256] = se[(long)bn * DD + t + 256];
  __syncthreads();
  float acc = 0.f;
  for (int k = 0; k < DD; ++k) acc = fmaf(ses[k], w1[(long)k * AH + t], acc);
  float v = tanhf(acc) * w2[t];
#pragma unroll
  for (int o = 32; o > 0; o >>= 1) v += __shfl_xor(v, o, 64);
  if ((t & 63) == 0) red[t >> 6] = v;
  __syncthreads();
  if (t == 0) alpha[bn] = red[0] + red[1] + red[2] + red[3];
}

// ---- a[b][l][:] = sum_n sattw[b,n]*ss[b,n,l,:] -> f32 out; emit sattw f32 ----
__global__ __launch_bounds__(128) void mix_kernel(
    const float* __restrict__ xbuf, const float* __restrict__ alpha,
    float* __restrict__ abuf, float* __restrict__ outw)
{
  const int l = blockIdx.x, b = blockIdx.y;
  const float a0 = alpha[b * 3 + 0], a1 = alpha[b * 3 + 1], a2 = alpha[b * 3 + 2];
  const float mx = fmaxf(a0, fmaxf(a1, a2));
  const float e0 = __expf(a0 - mx), e1 = __expf(a1 - mx), e2 = __expf(a2 - mx);
  const float inv = 1.f / (e0 + e1 + e2);
  const float w0 = e0 * inv, w1 = e1 * inv, w2 = e2 * inv;
  const float4* x0 = (const float4*)(xbuf + (((long)b * 3 + 0) * LL + l) * DD);
  const float4* x1 = (const float4*)(xbuf + (((long)b * 3 + 1) * LL + l) * DD);
  const float4* x2 = (const float4*)(xbuf + (((long)b * 3 + 2) * LL + l) * DD);
  float4* ar = (float4*)(abuf + ((long)b * LL + l) * DD);
  const int t = threadIdx.x;
  float4 v0 = x0[t], v1 = x1[t], v2 = x2[t];
  float4 o;
  o.x = w0 * v0.x + w1 * v1.x + w2 * v2.x;
  o.y = w0 * v0.y + w1 * v1.y + w2 * v2.y;
  o.z = w0 * v0.z + w1 * v1.z + w2 * v2.z;
  o.w = w0 * v0.w + w1 * v1.w + w2 * v2.w;
  ar[t] = o;
  if (l == 0 && t < 3) {
    float wv = (t == 0) ? w0 : ((t == 1) ? w1 : w2);
    outw[b * 3 + t] = wv;
  }
}

extern "C" void kernel_launch(void* const* d_in, const int* in_sizes, int n_in,
                              void* d_out, int out_size, void* d_ws, size_t ws_size,
                              hipStream_t stream) {
  const float* seg = (const float*)d_in[0];
  const float* msk = (const float*)d_in[1];
  const float* se  = (const float*)d_in[2];
  const float* w1  = (const float*)d_in[3];
  const float* b1  = (const float*)d_in[4];
  const float* w2  = (const float*)d_in[5];
  const float* b2  = (const float*)d_in[6];
  const float* w3  = (const float*)d_in[7];
  const float* b3  = (const float*)d_in[8];
  const float* lcW = (const float*)d_in[9];
  const float* lcb = (const float*)d_in[10];
  const float* lvW = (const float*)d_in[11];
  const float* lvb = (const float*)d_in[12];
  const float* gcW = (const float*)d_in[13];
  const float* gcb = (const float*)d_in[14];
  const float* gvW = (const float*)d_in[15];
  const float* gvb = (const float*)d_in[16];
  const float* sw1 = (const float*)d_in[17];
  const float* sw2 = (const float*)d_in[18];
  float* out = (float*)d_out;                    // f32: [a (16*512*512) | sattw (48)]

  const long LD = (long)LL * DD;                 // 262144
  const long DDDD = (long)DD * DD;               // 262144
  float* ws = (float*)d_ws;
  float* xbuf = ws;                              // 12.58M f32 [0, 12.58M)
  float* scratch = xbuf + (long)BB * NSEG * LD;  // 12.58M (h1; later mk|ct)
  float* mkbuf = scratch;                        // B*L*D
  float* ctbuf = scratch + (long)BB * LD;        // B*L*2D
  float* h2buf = scratch + (long)BB * NSEG * LD; // 24K
  float* alphabuf = h2buf + (long)BB * NSEG * DD;// 48
  ushort_t* xb16 = (ushort_t*)(alphabuf + 64);   // 4.19M bf16 activation slot
  ushort_t* wbA = xb16 + (long)BB * LD;          // 524288 bf16 (c-weights)
  ushort_t* wbB = wbA + 2 * DDDD;                // 262144 bf16 (v-weights)
  // total ~27.7M f32-equiv = 110.8 MB
  // global-stage overlay (xbuf/scratch dead after mix): S | mkc | ctc
  float* Sbuf = ws;                              // 16.78M
  float* mkc  = ws + 16777216;                   // 2.1M
  float* ctc  = mkc + 2097152;                   // 4.19M

  dim3 g88(8, 8, BB), g168(16, 8, BB), blk(256);

  // ---- hyper path ----
  h2_kernel<<<BB * NSEG, 256, 0, stream>>>(se, w2, b2, h2buf);
  castb<<<2048, 256, 0, stream>>>(seg, 0, 22, xb16);                 // seg -> bf16
  for (int n = 0; n < NSEG; ++n) {
    castb<<<128, 256, 0, stream>>>(w1 + (long)n * DDDD, 0, 22, wbB);
    mfma_gemm<<<g88, blk, 0, stream>>>(xb16, wbB, b1 + n * DD,
                                       scratch + n * LD, DD, DD, LD, NSEG * LD, 1);
  }
  for (int n = 0; n < NSEG; ++n) {
    mult_cast<<<2048, 256, 0, stream>>>(scratch + n * LD, h2buf, n, xb16);
    castb<<<128, 256, 0, stream>>>(w3 + (long)n * DDDD, 0, 22, wbB);
    mfma_gemm<<<g88, blk, 0, stream>>>(xb16, wbB, b3 + n * DD,
                                       xbuf + n * LD, DD, DD, LD, NSEG * LD, 1);
  }

  // ---- local NL blocks ----
  for (int n = 0; n < NSEG; ++n)
    for (int s = 0; s < 2; ++s) {
      const int i = n * 2 + s;
      castb<<<2048, 256, 0, stream>>>(xbuf + n * LD, NSEG * LD, 15, xb16);
      castb<<<128, 256, 0, stream>>>(lvW + (long)i * DDDD, 0, 22, wbB);
      castb<<<256, 256, 0, stream>>>(lcW + (long)i * 2 * DDDD, 0, 22, wbA);
      mfma_gemm<<<g88, blk, 0, stream>>>(xb16, wbB, lvb + (long)i * DD,
                                         mkbuf, DD, DD, LD, LD, 0);
      mfma_gemm<<<g168, blk, 0, stream>>>(xb16, wbA, lcb + (long)i * 2 * DD,
                                          ctbuf, 2 * DD, DD, LD, 2 * LD, 0);
      local_attn<<<dim3(LL, BB), 512, 0, stream>>>(xbuf + n * LD, mkbuf, ctbuf, msk,
                                                   (long)NSEG * LD);
    }

  // ---- segment attention mix -> d_out ----
  alpha_kernel<<<BB * NSEG, 256, 0, stream>>>(se, sw1, sw2, alphabuf);
  mix_kernel<<<dim3(LL, BB), 128, 0, stream>>>(xbuf, alphabuf, out, out + 4194304);

  // ---- global NL blocks: per 8-batch chunk ----
  const int CHB = 8;
  for (int s = 0; s < 2; ++s) {
    castb<<<2048, 256, 0, stream>>>(out, 0, 22, xb16);               // a -> bf16 (all 16 b)
    castb<<<128, 256, 0, stream>>>(gvW + (long)s * DDDD, 0, 22, wbB);
    castb<<<256, 256, 0, stream>>>(gcW + (long)s * 2 * DDDD, 0, 22, wbA);
    for (int c = 0; c < BB / CHB; ++c) {
      const int b0 = c * CHB;
      mfma_gemm<<<dim3(8, 8, CHB), blk, 0, stream>>>(
          xb16 + (long)b0 * LD, wbB, gvb + (long)s * DD, mkc, DD, DD, LD, LD, 0);
      mfma_gemm<<<dim3(16, 8, CHB), blk, 0, stream>>>(
          xb16 + (long)b0 * LD, wbA, gcb + (long)s * 2 * DD, ctc,
          2 * DD, DD, LD, 2 * LD, 0);
      score_kernel<<<dim3(8, 8, CHB * NH), blk, 0, stream>>>(mkc, ctc, msk, Sbuf, b0);
      smax_kernel<<<CHB * NH * LL / 4, 256, 0, stream>>>(Sbuf);
      pv_kernel<<<dim3(8, CHB * NH), blk, 0, stream>>>(Sbuf, ctc, out, b0);
    }
  }
}